// Round 3
// baseline (113.954 us; speedup 1.0000x reference)
//
#include <hip/hip_runtime.h>

// NegativeSelection: score[i] = max(min_j ||x_i - s_j|| - 0.1, 0)
// N=16384, M=8192, D=128, fp32 in/out.
//
// Strategy: d2 = a2 + b2 - 2*dot. dot via fp16 MFMA (32x32x16), A pre-negated
// so acc = C_init(b2/2) + (-x)·s = b2/2 - dot; min over j tracked per row.
// final: d2 = a2 + 2*min, score = max(sqrt(max(d2,0)) - 0.1, 0).
//
// This revision: NO LDS staging in min_gemm. B (2 MB) is L2-resident per XCD
// (every block streams the same tiles), so fragments are loaded straight from
// L2 into registers — no barriers, no global_load_lds, no LDS pipe contention
// with MFMA operand reads. Waves run free; loads hoist under MFMAs.
//
// ws layout: Aws fp16 [N*128] (4 MB, tiled [k8][row][8], NEGATED)
//            Bws fp16 [M*128] (2 MB, same tiling)
//            b2h  f32 [M]     (0.5*rownorm² of self)
//            Pmin f32 [N*8]   (partial mins: 4 slices × 2 col-waves)
//            a2   f32 [N]     (rownorm² of x)
// total ~7.0 MB.

using half_t = _Float16;
typedef _Float16 half8 __attribute__((ext_vector_type(8)));
typedef float floatx16 __attribute__((ext_vector_type(16)));

#define TILE_ELEMS (128 * 128)

// One block per 128x128 tile. Converts fp32 -> fp16 into tiled layout
// [k8][row][8] (chunk c = k8*128+row stored at element c*8). A is negated.
// B tiles: b2h = 0.5 * sum(row^2). A tiles: a2 = sum(row^2).
__global__ __launch_bounds__(256) void prep_kernel(
    const float* __restrict__ x, const float* __restrict__ self,
    half_t* __restrict__ Aws, half_t* __restrict__ Bws,
    float* __restrict__ b2h, float* __restrict__ a2, int Atiles)
{
    __shared__ float part[256];
    int tile = blockIdx.x;
    int tid  = threadIdx.x;
    bool isB = tile >= Atiles;
    int bt   = tile - Atiles;
    const float* src = isB ? (self + (size_t)bt * TILE_ELEMS)
                           : (x    + (size_t)tile * TILE_ELEMS);
    half_t* dst = isB ? (Bws + (size_t)bt * TILE_ELEMS)
                      : (Aws + (size_t)tile * TILE_ELEMS);
    float sgn = isB ? 1.f : -1.f;

    int rowt = tid & 127;       // this thread's row (constant across i)
    int k8b  = tid >> 7;        // 0 or 1
    float ss = 0.f;
    #pragma unroll
    for (int i = 0; i < 8; ++i) {
        int k8 = i * 2 + k8b;
        const float4* p = (const float4*)(src + rowt * 128 + k8 * 8);
        float4 f0 = p[0];
        float4 f1 = p[1];
        half8 h;
        h[0] = (half_t)(sgn * f0.x); h[1] = (half_t)(sgn * f0.y);
        h[2] = (half_t)(sgn * f0.z); h[3] = (half_t)(sgn * f0.w);
        h[4] = (half_t)(sgn * f1.x); h[5] = (half_t)(sgn * f1.y);
        h[6] = (half_t)(sgn * f1.z); h[7] = (half_t)(sgn * f1.w);
        *(half8*)(dst + (size_t)(i * 256 + tid) * 8) = h;  // identity: coalesced
        ss += f0.x*f0.x + f0.y*f0.y + f0.z*f0.z + f0.w*f0.w;
        ss += f1.x*f1.x + f1.y*f1.y + f1.z*f1.z + f1.w*f1.w;
    }
    part[tid] = ss;
    __syncthreads();
    if (tid < 128) {
        float tot = part[tid] + part[tid + 128];
        if (isB) b2h[bt * 128 + tid] = 0.5f * tot;
        else     a2[tile * 128 + tid] = tot;
    }
}

// Grid: (N/128 row-blocks, 4 M-slices). Block 256 = 4 waves in 2x2.
// Wave (wr,wc) computes rows wr*64..+64 x cols wc*64..+64 per B tile.
// A fragments in registers for the whole block; B fragments loaded directly
// from L2 (Bws is 2 MB, resident per XCD). No LDS, no barriers in the loop —
// each wave is an independent load+MFMA stream.
__global__ __launch_bounds__(256, 2) void min_gemm_kernel(
    const half_t* __restrict__ Aws, const half_t* __restrict__ Bws,
    const float* __restrict__ b2h, float* __restrict__ Pmin,
    int Mslice)
{
    int tid  = threadIdx.x;
    int lane = tid & 63;
    int wid  = tid >> 6;
    int wr   = wid >> 1, wc = wid & 1;
    int ln31 = lane & 31, lh = lane >> 5;

    // A fragments: rows wr*64 + rt*32 + ln31, k = k8*8.., held in regs.
    const half_t* Atile = Aws + (size_t)blockIdx.x * TILE_ELEMS;
    half8 areg[2][8];
    #pragma unroll
    for (int rt = 0; rt < 2; ++rt)
        #pragma unroll
        for (int ki = 0; ki < 8; ++ki) {
            int k8  = ki * 2 + lh;
            int row = wr * 64 + rt * 32 + ln31;
            areg[rt][ki] = *(const half8*)(Atile + (size_t)(k8 * 128 + row) * 8);
        }

    float minacc[2][16];
    #pragma unroll
    for (int rt = 0; rt < 2; ++rt)
        #pragma unroll
        for (int r = 0; r < 16; ++r) minacc[rt][r] = 1e30f;

    int iters = Mslice >> 7;
    int s = blockIdx.y;
    const half_t* Bbase = Bws + (size_t)s * iters * TILE_ELEMS;

    for (int it = 0; it < iters; ++it) {
        const half_t* Bt = Bbase + (size_t)it * TILE_ELEMS;

        // 16 coalesced 16B loads from L2 — no barrier above can stop the
        // compiler from issuing these as early as registers allow.
        half8 bf0[8], bf1[8];
        #pragma unroll
        for (int ki = 0; ki < 8; ++ki) {
            int k8 = ki * 2 + lh;
            bf0[ki] = *(const half8*)(Bt + (size_t)(k8 * 128 + wc * 64 + ln31) * 8);
            bf1[ki] = *(const half8*)(Bt + (size_t)(k8 * 128 + wc * 64 + 32 + ln31) * 8);
        }

        int colbase = s * Mslice + it * 128 + wc * 64 + ln31;
        float b2v0 = b2h[colbase];
        float b2v1 = b2h[colbase + 32];

        // Broadcast b2/2 into C vectors; ki=0 peeled so these feed the
        // MFMA C operand directly.
        floatx16 c0, c1;
        #pragma unroll
        for (int r = 0; r < 16; ++r) { c0[r] = b2v0; c1[r] = b2v1; }

        floatx16 acc00, acc01, acc10, acc11;
        acc00 = __builtin_amdgcn_mfma_f32_32x32x16_f16(areg[0][0], bf0[0], c0, 0, 0, 0);
        acc01 = __builtin_amdgcn_mfma_f32_32x32x16_f16(areg[0][0], bf1[0], c1, 0, 0, 0);
        acc10 = __builtin_amdgcn_mfma_f32_32x32x16_f16(areg[1][0], bf0[0], c0, 0, 0, 0);
        acc11 = __builtin_amdgcn_mfma_f32_32x32x16_f16(areg[1][0], bf1[0], c1, 0, 0, 0);
        #pragma unroll
        for (int ki = 1; ki < 8; ++ki) {
            acc00 = __builtin_amdgcn_mfma_f32_32x32x16_f16(areg[0][ki], bf0[ki], acc00, 0, 0, 0);
            acc01 = __builtin_amdgcn_mfma_f32_32x32x16_f16(areg[0][ki], bf1[ki], acc01, 0, 0, 0);
            acc10 = __builtin_amdgcn_mfma_f32_32x32x16_f16(areg[1][ki], bf0[ki], acc10, 0, 0, 0);
            acc11 = __builtin_amdgcn_mfma_f32_32x32x16_f16(areg[1][ki], bf1[ki], acc11, 0, 0, 0);
        }

        // acc = b2/2 - dot; fold into running per-row min (min3-fusible).
        #pragma unroll
        for (int r = 0; r < 16; ++r) {
            minacc[0][r] = fminf(fminf(acc00[r], acc01[r]), minacc[0][r]);
            minacc[1][r] = fminf(fminf(acc10[r], acc11[r]), minacc[1][r]);
        }
    }

    // min across the 32 column-lanes; C/D row = (r&3) + 8*(r>>2) + 4*lh.
    #pragma unroll
    for (int rt = 0; rt < 2; ++rt)
        #pragma unroll
        for (int r = 0; r < 16; ++r) {
            float v = minacc[rt][r];
            #pragma unroll
            for (int m = 1; m < 32; m <<= 1)
                v = fminf(v, __shfl_xor(v, m, 64));
            if (ln31 == 0) {
                int row = blockIdx.x * 128 + wr * 64 + rt * 32
                        + (r & 3) + 8 * (r >> 2) + 4 * lh;
                Pmin[(size_t)row * 8 + s * 2 + wc] = v;
            }
        }
}

// One thread per row: min of 8 partials, d2 = a2 + 2*min, sqrt/shift/clamp.
__global__ __launch_bounds__(256) void final_kernel(
    const float* __restrict__ a2, const float* __restrict__ Pmin,
    float* __restrict__ out)
{
    int row = blockIdx.x * 256 + threadIdx.x;
    const float4* pp = (const float4*)(Pmin + (size_t)row * 8);
    float4 p0 = pp[0];
    float4 p1 = pp[1];
    float p = fminf(fminf(fminf(p0.x, p0.y), fminf(p0.z, p0.w)),
                    fminf(fminf(p1.x, p1.y), fminf(p1.z, p1.w)));
    float d2 = a2[row] + 2.f * p;          // a2 + 2*(b2/2 - dot)
    float d  = sqrtf(fmaxf(d2, 0.f));
    out[row] = fmaxf(d - 0.1f, 0.f);
}

extern "C" void kernel_launch(void* const* d_in, const int* in_sizes, int n_in,
                              void* d_out, int out_size, void* d_ws, size_t ws_size,
                              hipStream_t stream)
{
    const float* x    = (const float*)d_in[0];
    const float* self = (const float*)d_in[1];
    float* out        = (float*)d_out;

    int N = in_sizes[0] / 128;   // 16384
    int M = in_sizes[1] / 128;   // 8192
    int Atiles = N / 128;        // 128
    int Btiles = M / 128;        // 64

    char* w      = (char*)d_ws;
    half_t* Aws  = (half_t*)w;
    half_t* Bws  = Aws + (size_t)N * 128;
    float*  b2h  = (float*)(w + (size_t)(N + M) * 128 * 2);
    float*  Pmin = b2h + M;
    float*  a2   = Pmin + (size_t)N * 8;
    // ws required: 4 MB + 2 MB + 32 KB + 512 KB + 64 KB ≈ 7.0 MB

    prep_kernel<<<Atiles + Btiles, 256, 0, stream>>>(x, self, Aws, Bws, b2h, a2, Atiles);

    int Mslice = M / 4;          // 2048 -> 16 iterations/block
    dim3 grid(Atiles, 4);        // 512 blocks = 2/CU
    min_gemm_kernel<<<grid, 256, 0, stream>>>(Aws, Bws, b2h, Pmin, Mslice);

    final_kernel<<<N / 256, 256, 0, stream>>>(a2, Pmin, out);
}

// Round 4
// 100.157 us; speedup vs baseline: 1.1378x; 1.1378x over previous
//
#include <hip/hip_runtime.h>

// NegativeSelection: score[i] = max(min_j ||x_i - s_j|| - 0.1, 0)
// N=16384, M=8192, D=128, fp32 in/out.
//
// d2 = a2 + b2 - 2*dot. dot via fp16 MFMA (32x32x16), A pre-negated so
// acc = C_init(b2/2) + (-x)·s = b2/2 - dot; min over j tracked per row.
// final: d2 = a2 + 2*min, score = max(sqrt(max(d2,0)) - 0.1, 0).
//
// This revision (counted-vmcnt ring pipeline, 256-row blocks):
//  - 8 waves/block (wr 0..3 x wc 0..1), 256 rows share each 32 KB B tile
//    -> 2x arithmetic intensity vs 128-row blocks.
//  - 3-buffer LDS ring, stage(t+2) issued at iter t via global_load_lds;
//    raw s_barrier + s_waitcnt vmcnt(4) (never 0 mid-loop) so prefetch
//    stays in flight across barriers (T3/T4; escapes the ~900TF drain
//    ceiling of __syncthreads-based loops).
//  - b2 staged in LDS up-front so the vmcnt domain contains ONLY staging
//    loads (counted waits stay exact).
//  - lgkmcnt(0)+sched_barrier(0) bracket each barrier (race discipline).
//
// ws: Aws fp16 [N*128] (4 MB, [k8][row][8], NEGATED), Bws fp16 [M*128] (2 MB),
//     b2h f32 [M], Pmin f32 [N*8], a2 f32 [N]  -> ~7 MB.

using half_t = _Float16;
typedef _Float16 half8 __attribute__((ext_vector_type(8)));
typedef float floatx16 __attribute__((ext_vector_type(16)));

#define TILE_ELEMS (128 * 128)   // 32 KB fp16

__device__ __forceinline__ void async_load16(const void* g, void* l) {
    __builtin_amdgcn_global_load_lds(
        (const __attribute__((address_space(1))) void*)g,
        (__attribute__((address_space(3))) void*)l, 16, 0, 0);
}

// 512 threads stage one 32 KB tile: 4 chunks of 16 B per thread, linear.
__device__ __forceinline__ void stage_tile(const half_t* __restrict__ Bt,
                                           half_t* __restrict__ dst, int tid) {
    #pragma unroll
    for (int j = 0; j < 4; ++j) {
        int chunk = j * 512 + tid;
        async_load16(Bt + (size_t)chunk * 8, dst + (size_t)chunk * 8);
    }
}

// One block per 128x128 tile. fp32 -> fp16 tiled layout [k8][row][8]
// (chunk c = k8*128+row stored at element c*8). A negated.
// B tiles: b2h = 0.5*sum(row^2). A tiles: a2 = sum(row^2).
__global__ __launch_bounds__(256) void prep_kernel(
    const float* __restrict__ x, const float* __restrict__ self,
    half_t* __restrict__ Aws, half_t* __restrict__ Bws,
    float* __restrict__ b2h, float* __restrict__ a2, int Atiles)
{
    __shared__ float part[256];
    int tile = blockIdx.x;
    int tid  = threadIdx.x;
    bool isB = tile >= Atiles;
    int bt   = tile - Atiles;
    const float* src = isB ? (self + (size_t)bt * TILE_ELEMS)
                           : (x    + (size_t)tile * TILE_ELEMS);
    half_t* dst = isB ? (Bws + (size_t)bt * TILE_ELEMS)
                      : (Aws + (size_t)tile * TILE_ELEMS);
    float sgn = isB ? 1.f : -1.f;

    int rowt = tid & 127;
    int k8b  = tid >> 7;
    float ss = 0.f;
    #pragma unroll
    for (int i = 0; i < 8; ++i) {
        int k8 = i * 2 + k8b;
        const float4* p = (const float4*)(src + rowt * 128 + k8 * 8);
        float4 f0 = p[0];
        float4 f1 = p[1];
        half8 h;
        h[0] = (half_t)(sgn * f0.x); h[1] = (half_t)(sgn * f0.y);
        h[2] = (half_t)(sgn * f0.z); h[3] = (half_t)(sgn * f0.w);
        h[4] = (half_t)(sgn * f1.x); h[5] = (half_t)(sgn * f1.y);
        h[6] = (half_t)(sgn * f1.z); h[7] = (half_t)(sgn * f1.w);
        *(half8*)(dst + (size_t)(i * 256 + tid) * 8) = h;
        ss += f0.x*f0.x + f0.y*f0.y + f0.z*f0.z + f0.w*f0.w;
        ss += f1.x*f1.x + f1.y*f1.y + f1.z*f1.z + f1.w*f1.w;
    }
    part[tid] = ss;
    __syncthreads();
    if (tid < 128) {
        float tot = part[tid] + part[tid + 128];
        if (isB) b2h[bt * 128 + tid] = 0.5f * tot;
        else     a2[tile * 128 + tid] = tot;
    }
}

// One pipeline iteration. VN = vmcnt allowance at the top (4 mid-loop:
// tile t's 4 loads retired, tile t+1's may remain in flight; 0 last iter).
template<int VN>
__device__ __forceinline__ void gemm_iter(
    int t, int iters, int tid, int wc, int ln31, int lh,
    const half_t* __restrict__ Bbase, half_t (*ring)[TILE_ELEMS],
    const float* __restrict__ b2sh,
    const half8 (&areg)[2][8], float (&minacc)[2][16])
{
    __builtin_amdgcn_sched_barrier(0);
    if constexpr (VN == 4) asm volatile("s_waitcnt vmcnt(4)" ::: "memory");
    else                   asm volatile("s_waitcnt vmcnt(0)" ::: "memory");
    asm volatile("s_waitcnt lgkmcnt(0)" ::: "memory");
    __builtin_amdgcn_s_barrier();   // collective: tile t readable; ring[(t+2)%3] free
    __builtin_amdgcn_sched_barrier(0);

    // Stage tile t+2 into the buffer last read at iter t-1 (barrier above
    // guarantees those reads retired in every wave).
    if (t + 2 < iters)
        stage_tile(Bbase + (size_t)(t + 2) * TILE_ELEMS, &ring[(t + 2) % 3][0], tid);

    const half_t* Bs = &ring[t % 3][0];
    float b2v0 = b2sh[t * 128 + wc * 64 + ln31];
    float b2v1 = b2sh[t * 128 + wc * 64 + 32 + ln31];

    floatx16 c0, c1;
    #pragma unroll
    for (int r = 0; r < 16; ++r) { c0[r] = b2v0; c1[r] = b2v1; }

    floatx16 acc00, acc01, acc10, acc11;
    {
        half8 bf0 = *(const half8*)(Bs + (size_t)(lh * 128 + wc * 64 + ln31) * 8);
        half8 bf1 = *(const half8*)(Bs + (size_t)(lh * 128 + wc * 64 + 32 + ln31) * 8);
        acc00 = __builtin_amdgcn_mfma_f32_32x32x16_f16(areg[0][0], bf0, c0, 0, 0, 0);
        acc01 = __builtin_amdgcn_mfma_f32_32x32x16_f16(areg[0][0], bf1, c1, 0, 0, 0);
        acc10 = __builtin_amdgcn_mfma_f32_32x32x16_f16(areg[1][0], bf0, c0, 0, 0, 0);
        acc11 = __builtin_amdgcn_mfma_f32_32x32x16_f16(areg[1][0], bf1, c1, 0, 0, 0);
    }
    #pragma unroll
    for (int ki = 1; ki < 8; ++ki) {
        half8 bf0 = *(const half8*)(Bs + (size_t)((ki * 2 + lh) * 128 + wc * 64 + ln31) * 8);
        half8 bf1 = *(const half8*)(Bs + (size_t)((ki * 2 + lh) * 128 + wc * 64 + 32 + ln31) * 8);
        acc00 = __builtin_amdgcn_mfma_f32_32x32x16_f16(areg[0][ki], bf0, acc00, 0, 0, 0);
        acc01 = __builtin_amdgcn_mfma_f32_32x32x16_f16(areg[0][ki], bf1, acc01, 0, 0, 0);
        acc10 = __builtin_amdgcn_mfma_f32_32x32x16_f16(areg[1][ki], bf0, acc10, 0, 0, 0);
        acc11 = __builtin_amdgcn_mfma_f32_32x32x16_f16(areg[1][ki], bf1, acc11, 0, 0, 0);
    }

    #pragma unroll
    for (int r = 0; r < 16; ++r) {
        minacc[0][r] = fminf(fminf(acc00[r], acc01[r]), minacc[0][r]);
        minacc[1][r] = fminf(fminf(acc10[r], acc11[r]), minacc[1][r]);
    }
}

// Grid: (N/256, 4 M-slices), 512 threads = 8 waves (wr 0..3 x wc 0..1).
// Wave (wr,wc): rows wr*64..+64 (2 A tiles per block), cols wc*64..+64.
__global__ __launch_bounds__(512, 2) void min_gemm_kernel(
    const half_t* __restrict__ Aws, const half_t* __restrict__ Bws,
    const float* __restrict__ b2h, float* __restrict__ Pmin, int Mslice)
{
    __shared__ half_t ring[3][TILE_ELEMS];   // 96 KB
    __shared__ float  b2sh[2048];            // 8 KB (Mslice = 2048)

    int tid  = threadIdx.x;
    int lane = tid & 63;
    int wid  = tid >> 6;
    int wr   = wid >> 1, wc = wid & 1;
    int ln31 = lane & 31, lh = lane >> 5;

    // A fragments: 256 rows/block = A tiles 2bx, 2bx+1. Held in regs.
    const half_t* Atile = Aws + (size_t)(blockIdx.x * 2 + (wr >> 1)) * TILE_ELEMS;
    int rbase = (wr & 1) * 64;
    half8 areg[2][8];
    #pragma unroll
    for (int rt = 0; rt < 2; ++rt)
        #pragma unroll
        for (int ki = 0; ki < 8; ++ki)
            areg[rt][ki] = *(const half8*)(
                Atile + (size_t)((ki * 2 + lh) * 128 + rbase + rt * 32 + ln31) * 8);

    // b2 slice -> LDS (keeps the main-loop vmcnt domain staging-only).
    int s = blockIdx.y;
    for (int j = tid; j < Mslice; j += 512)
        b2sh[j] = b2h[s * Mslice + j];

    float minacc[2][16];
    #pragma unroll
    for (int rt = 0; rt < 2; ++rt)
        #pragma unroll
        for (int r = 0; r < 16; ++r) minacc[rt][r] = 1e30f;

    int iters = Mslice >> 7;   // 16
    const half_t* Bbase = Bws + (size_t)s * iters * TILE_ELEMS;

    __syncthreads();   // b2sh visible; vmcnt/lgkm fully drained (once)

    // Prologue: 2-deep prefetch.
    stage_tile(Bbase,              &ring[0][0], tid);
    stage_tile(Bbase + TILE_ELEMS, &ring[1][0], tid);

    for (int t = 0; t < iters - 1; ++t)
        gemm_iter<4>(t, iters, tid, wc, ln31, lh, Bbase, ring, b2sh, areg, minacc);
    gemm_iter<0>(iters - 1, iters, tid, wc, ln31, lh, Bbase, ring, b2sh, areg, minacc);

    // min across 32 column-lanes; C/D row = (r&3) + 8*(r>>2) + 4*lh.
    #pragma unroll
    for (int rt = 0; rt < 2; ++rt)
        #pragma unroll
        for (int r = 0; r < 16; ++r) {
            float v = minacc[rt][r];
            #pragma unroll
            for (int m = 1; m < 32; m <<= 1)
                v = fminf(v, __shfl_xor(v, m, 64));
            if (ln31 == 0) {
                int row = blockIdx.x * 256 + wr * 64 + rt * 32
                        + (r & 3) + 8 * (r >> 2) + 4 * lh;
                Pmin[(size_t)row * 8 + s * 2 + wc] = v;
            }
        }
}

// One thread per row: min of 8 partials, d2 = a2 + 2*min, sqrt/shift/clamp.
__global__ __launch_bounds__(256) void final_kernel(
    const float* __restrict__ a2, const float* __restrict__ Pmin,
    float* __restrict__ out)
{
    int row = blockIdx.x * 256 + threadIdx.x;
    const float4* pp = (const float4*)(Pmin + (size_t)row * 8);
    float4 p0 = pp[0];
    float4 p1 = pp[1];
    float p = fminf(fminf(fminf(p0.x, p0.y), fminf(p0.z, p0.w)),
                    fminf(fminf(p1.x, p1.y), fminf(p1.z, p1.w)));
    float d2 = a2[row] + 2.f * p;
    float d  = sqrtf(fmaxf(d2, 0.f));
    out[row] = fmaxf(d - 0.1f, 0.f);
}

extern "C" void kernel_launch(void* const* d_in, const int* in_sizes, int n_in,
                              void* d_out, int out_size, void* d_ws, size_t ws_size,
                              hipStream_t stream)
{
    const float* x    = (const float*)d_in[0];
    const float* self = (const float*)d_in[1];
    float* out        = (float*)d_out;

    int N = in_sizes[0] / 128;   // 16384
    int M = in_sizes[1] / 128;   // 8192
    int Atiles = N / 128;        // 128
    int Btiles = M / 128;        // 64

    char* w      = (char*)d_ws;
    half_t* Aws  = (half_t*)w;
    half_t* Bws  = Aws + (size_t)N * 128;
    float*  b2h  = (float*)(w + (size_t)(N + M) * 128 * 2);
    float*  Pmin = b2h + M;
    float*  a2   = Pmin + (size_t)N * 8;
    // ws: 4 MB + 2 MB + 32 KB + 512 KB + 64 KB ≈ 7 MB

    prep_kernel<<<Atiles + Btiles, 256, 0, stream>>>(x, self, Aws, Bws, b2h, a2, Atiles);

    int Mslice = M / 4;          // 2048 -> 16 tile-iterations
    dim3 grid(N / 256, 4);       // 256 blocks = exactly 1/CU, 8 waves each
    min_gemm_kernel<<<grid, 512, 0, stream>>>(Aws, Bws, b2h, Pmin, Mslice);

    final_kernel<<<N / 256, 256, 0, stream>>>(a2, Pmin, out);
}